// Round 10
// baseline (69.495 us; speedup 1.0000x reference)
//
#include <hip/hip_runtime.h>
#include <cstdint>

// CovNet BNN: out = clip(x @ sign(W1)^T + b1, ±1) @ W2^T + b2
// B=8192, IN=784, HID=4096, OUT=10.
// R10 = the untried combo of three verified elements:
//   (1) 16x16x32 frags, zero re-reads: per tile 2 kk-phases, each reads
//       af[8]+bf[4] once (24 b128/wave/tile) -- R8's low-conflict pattern.
//   (2) fragment read-ahead (R6): phase k+1's 12 ds_read issue BEFORE phase
//       k's 32 MFMAs -> LDS pipe and MFMA pipe always co-resident.
//   (3) ring-3 B + ONE counted vmcnt(4) per tile, never 0 mid-loop (m218).
// Per-tile schedule (buf p = t&1, B slot bs = t%3):
//   RD12(S1, p, bs, kk1)                 // own second-half frags
//   stA(t+1)            [4 gl_lds]
//   MFMA32(S0)                           // first-half (read at end of t-1)
//   stB(t+2, (t+2)%3)   [4 gl_lds]
//   WAITL0 (+schedbar)                   // S1 reads landed
//   WAITV(4)  [t==11: 0; t==12: skip]    // certs A(t+1),B(t+1); B(t+2) flies
//   BARRIER                              // next-tile bufs valid chip-wide
//   RD12(S0, p^1, (t+1)%3, kk0)          // next tile first-half
//   MFMA32(S1)
// vmcnt ledger at tile t's WAITV: outstanding = B(t+1)[staged t-1] +
//   A(t+1)[this tile] + B(t+2)[this tile] = 12; WAITV(4) certs oldest 8 =
//   B(t+1),A(t+1); leaves B(t+2) in flight. Slacks >= 1 full tile > HBM 900cy.
// WAR: stA(t+1) overwrites A(t-1) -- last read RD12(S1) at t-1, covered by
//   t-1's WAITL0 + BARRIER before this stage issues (+>=300cy landing).
//   stB(t+2) -> slot (t+2)%3 holds B(t-1), same argument.
// Prologue: stA(0); stB(0,s0); stB(1,s1); WAITV(4) certs A(0),B(0), B(1)
//   flies; BARRIER; RD12(S0, buf0, s0, kk0). Tail t=11: WAITV(0); t=12: no
//   stages/wait/barrier; epilogue begins with WAITL0+BARRIER.
// Epilogue: R8 verbatim (fused GEMM2 via LDS, passed R2-R9, absmax 0.0625).

#define BATCH 8192
#define IN_F  784
#define HID   4096
#define OUT_F 10
#define KP    832     // padded K = 13*64
#define NKT   13
#define BM    256
#define BN    256
#define BK    64
#define NCT   (HID / BN)   // 16 col tiles
#define HCS   264          // epilogue hc row stride (f16)

typedef unsigned short u16;
typedef __attribute__((ext_vector_type(4))) unsigned short u16x4;
typedef __attribute__((ext_vector_type(8)))  _Float16 f16x8;
typedef __attribute__((ext_vector_type(4)))  float    f32x4;

#define BARRIER() do { asm volatile("" ::: "memory"); \
                       __builtin_amdgcn_s_barrier();  \
                       asm volatile("" ::: "memory"); } while (0)
#define WAITV(n)  asm volatile("s_waitcnt vmcnt(" #n ")" ::: "memory")
#define WAITL0()  do { asm volatile("s_waitcnt lgkmcnt(0)" ::: "memory"); \
                       __builtin_amdgcn_sched_barrier(0); } while (0)

__device__ __forceinline__ u16 f2h(float f) {
  union { _Float16 h; u16 u; } c;
  c.h = (_Float16)f;   // RNE
  return c.u;
}

__device__ __forceinline__ void gl_lds16(const void* g, void* l) {
  __builtin_amdgcn_global_load_lds(
      (const __attribute__((address_space(1))) uint32_t*)g,
      (__attribute__((address_space(3))) uint32_t*)l, 16, 0, 0);
}

// ---------------- prep: x -> f16 (padded), W1 -> sign f16 (padded), W2 -> [16][4096]
__global__ void prep_kernel(const float* __restrict__ x, const float* __restrict__ W1,
                            const float* __restrict__ W2,
                            u16* __restrict__ xh, u16* __restrict__ wh,
                            u16* __restrict__ w2h) {
  const int stride = gridDim.x * blockDim.x;
  const int gid = blockIdx.x * blockDim.x + threadIdx.x;
  const int KP4 = KP / 4;    // 208
  const int IN4 = IN_F / 4;  // 196
  const float4* x4 = (const float4*)x;
  const float4* w4 = (const float4*)W1;
  for (int i = gid; i < BATCH * KP4; i += stride) {
    int b = i / KP4, k = i - b * KP4;
    u16x4 o = {0, 0, 0, 0};
    if (k < IN4) {
      float4 v = x4[(size_t)b * IN4 + k];
      o[0] = f2h(v.x); o[1] = f2h(v.y); o[2] = f2h(v.z); o[3] = f2h(v.w);
    }
    *(u16x4*)&xh[(size_t)b * KP + k * 4] = o;
  }
  for (int i = gid; i < HID * KP4; i += stride) {
    int h = i / KP4, k = i - h * KP4;
    u16x4 o = {0, 0, 0, 0};
    if (k < IN4) {
      float4 v = w4[(size_t)h * IN4 + k];
      o[0] = v.x > 0.f ? 0x3C00 : (v.x < 0.f ? 0xBC00 : 0);
      o[1] = v.y > 0.f ? 0x3C00 : (v.y < 0.f ? 0xBC00 : 0);
      o[2] = v.z > 0.f ? 0x3C00 : (v.z < 0.f ? 0xBC00 : 0);
      o[3] = v.w > 0.f ? 0x3C00 : (v.w < 0.f ? 0xBC00 : 0);
    }
    *(u16x4*)&wh[(size_t)h * KP + k * 4] = o;
  }
  for (int i = gid; i < 16 * HID; i += stride) {
    int o = i >> 12, k = i & (HID - 1);
    w2h[i] = (o < OUT_F) ? f2h(W2[o * HID + k]) : (u16)0;
  }
}

// ---------------- main fused GEMM (256x256, 8 waves, 16x16x32, R10 pipeline)
__global__ void __launch_bounds__(512, 1) gemm_kernel(
    const u16* __restrict__ xh, const u16* __restrict__ wh,
    const u16* __restrict__ w2h, const float* __restrict__ b1,
    float* __restrict__ part) {
  __shared__ union {
    struct { u16 A[2][BM * BK]; u16 B[3][BN * BK]; } m;   // 64+96 = 160 KiB
    struct { u16 hc[128 * HCS]; u16 w2[16 * 256]; } e;    // ~74 KiB
  } sm;

  const int t   = threadIdx.x;
  const int ct  = blockIdx.x;   // col tile (HID), 0..15
  const int br  = blockIdx.y;   // row tile (BATCH), 0..31
  const int w   = t >> 6;       // wave 0..7
  const int l   = t & 63;
  const int wm  = w >> 2;       // 0..1: wave rows = wm*128 + mi*16 (mi 0..7)
  const int wn  = w & 3;        // 0..3: wave cols = wn*64  + nj*16 (nj 0..3)
  const int g   = l >> 4;
  const int r16 = l & 15;
  const int swz = (r16 & 7) << 3;   // f16-unit XOR (16B-slot granule)

  // staging: thread t covers 16B; per 64-row chunk: row = t>>3; source slot
  // pre-swizzled (rule #21): logical slot = (t&7)^(row&7); LDS dest linear.
  const int  srow  = t >> 3;
  const int  sslot = (t & 7) ^ (srow & 7);
  const u16* gA = xh + (size_t)(br * BM) * KP + sslot * 8;
  const u16* gB = wh + (size_t)(ct * BN) * KP + sslot * 8;

  auto stA = [&](int tile) {          // full A tile -> ring slot tile&1 (4 ops)
    const int b = tile & 1;
#pragma unroll
    for (int c = 0; c < 4; ++c)
      gl_lds16(gA + (size_t)(c * 64 + srow) * KP + tile * BK,
               &sm.m.A[b][c * 4096 + t * 8]);
  };
  auto stB = [&](int tile, int s) {   // full B tile -> ring slot s (4 ops)
#pragma unroll
    for (int c = 0; c < 4; ++c)
      gl_lds16(gB + (size_t)(c * 64 + srow) * KP + tile * BK,
               &sm.m.B[s][c * 4096 + t * 8]);
  };
  // reads apply the same XOR involution: phys slot = logical slot ^ (row&7)
  auto rdA = [&](int p, int mi, int kk) -> f16x8 {
    int row = wm * 128 + mi * 16 + r16;
    return *(const f16x8*)&sm.m.A[p][row * 64 + ((kk * 32 + g * 8) ^ swz)];
  };
  auto rdB = [&](int s, int nj, int kk) -> f16x8 {
    int row = wn * 64 + nj * 16 + r16;
    return *(const f16x8*)&sm.m.B[s][row * 64 + ((kk * 32 + g * 8) ^ swz)];
  };

  f32x4 acc[8][4] = {};       // [mi][nj]
  f16x8 af[2][8], bf[2][4];   // two named frag sets, static indices only

#define RD12(S, P, BS, KK) do {                                       \
    _Pragma("unroll") for (int mi_ = 0; mi_ < 8; ++mi_) af[S][mi_] = rdA(P, mi_, KK); \
    _Pragma("unroll") for (int nj_ = 0; nj_ < 4; ++nj_) bf[S][nj_] = rdB(BS, nj_, KK); \
  } while (0)
#define MFMA32(S) do {                                                \
    __builtin_amdgcn_s_setprio(1);                                    \
    _Pragma("unroll") for (int mi_ = 0; mi_ < 8; ++mi_)               \
      _Pragma("unroll") for (int nj_ = 0; nj_ < 4; ++nj_)             \
        acc[mi_][nj_] = __builtin_amdgcn_mfma_f32_16x16x32_f16(       \
            af[S][mi_], bf[S][nj_], acc[mi_][nj_], 0, 0, 0);          \
    __builtin_amdgcn_s_setprio(0);                                    \
  } while (0)

  // prologue: A(0),B(0) certified; B(1) stays in flight past the wait
  stA(0);
  stB(0, 0);
  stB(1, 1);
  WAITV(4);
  BARRIER();
  RD12(0, 0, 0, 0);   // tile 0 first-half frags

  int bs = 0;   // tt % 3
  for (int tt = 0; tt < NKT; ++tt) {
    const int p   = tt & 1;
    const int bs1 = (bs == 2) ? 0 : bs + 1;   // (tt+1) % 3
    const int bs2 = (bs == 0) ? 2 : bs - 1;   // (tt+2) % 3

    RD12(1, p, bs, 1);                 // own second-half frags
    if (tt + 1 < NKT) stA(tt + 1);
    MFMA32(0);                         // first-half (frags from end of t-1)
    if (tt + 2 < NKT) stB(tt + 2, bs2);
    WAITL0();                          // S1 reads landed
    if      (tt < NKT - 2) { WAITV(4); }   // certs A(t+1),B(t+1); B(t+2) flies
    else if (tt == NKT - 2) { WAITV(0); }  // tail drain
    if (tt + 1 < NKT) {
      BARRIER();                       // next-tile buffers valid chip-wide
      RD12(0, p ^ 1, bs1, 0);          // next tile first-half frags
    }
    MFMA32(1);                         // second-half (registers only)

    bs = bs1;
  }

  // ---- epilogue: h = clip(acc + b1), fused GEMM2 through LDS (R8 verbatim) ----
  WAITL0();
  BARRIER();   // all waves' tile-12 reads drained; e.* overlays m.A/m.B
  {
    int row = t >> 5, sp = t & 31;
    int ls = (sp & 24) | ((sp ^ row) & 7);   // swizzled logical slot
    gl_lds16(w2h + (size_t)row * HID + ct * BN + ls * 8, &sm.e.w2[t * 8]);
  }
  float b1v[4];
#pragma unroll
  for (int ni = 0; ni < 4; ++ni) b1v[ni] = b1[ct * BN + wn * 64 + ni * 16 + r16];

  float* partBase = part + ((size_t)ct * BATCH + br * BM) * 16;

#pragma unroll
  for (int p = 0; p < 2; ++p) {
    if (p == 1) BARRIER();               // p=0 hc reads done before overwrite
    if (wm == p) {
#pragma unroll
      for (int mi = 0; mi < 8; ++mi)
#pragma unroll
        for (int ni = 0; ni < 4; ++ni)
#pragma unroll
          for (int r = 0; r < 4; ++r) {
            float v = acc[mi][ni][r] + b1v[ni];
            v = fminf(fmaxf(v, -1.f), 1.f);
            sm.e.hc[(mi * 16 + g * 4 + r) * HCS + wn * 64 + ni * 16 + r16] = f2h(v);
          }
    }
    if (p == 0) { WAITV(0); }            // w2 landed
    BARRIER();
    f32x4 acc2 = {};
#pragma unroll
    for (int kk = 0; kk < 8; ++kk) {
      f16x8 a2 = *(const f16x8*)&sm.e.hc[(w * 16 + r16) * HCS + kk * 32 + g * 8];
      int s   = kk * 4 + g;
      int sp2 = (s & 24) | ((s ^ r16) & 7);
      f16x8 b2f = *(const f16x8*)&sm.e.w2[r16 * 256 + sp2 * 8];
      acc2 = __builtin_amdgcn_mfma_f32_16x16x32_f16(a2, b2f, acc2, 0, 0, 0);
    }
#pragma unroll
    for (int r = 0; r < 4; ++r)
      partBase[(size_t)(p * 128 + w * 16 + g * 4 + r) * 16 + r16] = acc2[r];
  }
}

// ---------------- reduce partials over 16 col tiles + b2
__global__ void reduce_kernel(const float* __restrict__ part, const float* __restrict__ b2,
                              float* __restrict__ out) {
  int i = blockIdx.x * blockDim.x + threadIdx.x;
  if (i >= BATCH * OUT_F) return;
  int b = i / OUT_F, o = i - b * OUT_F;
  float acc = b2[o];
#pragma unroll
  for (int c = 0; c < NCT; ++c)
    acc += part[((size_t)c * BATCH + b) * 16 + o];
  out[i] = acc;
}

extern "C" void kernel_launch(void* const* d_in, const int* in_sizes, int n_in,
                              void* d_out, int out_size, void* d_ws, size_t ws_size,
                              hipStream_t stream) {
  const float* x  = (const float*)d_in[0];
  const float* W1 = (const float*)d_in[1];
  const float* b1 = (const float*)d_in[2];
  const float* W2 = (const float*)d_in[3];
  const float* b2 = (const float*)d_in[4];
  float* out = (float*)d_out;

  // ws layout (~29 MB): xh 13.6 MB | wh 6.8 MB | w2h 0.13 MB | part 8.4 MB
  u16* xh  = (u16*)d_ws;
  u16* wh  = xh + (size_t)BATCH * KP;
  u16* w2h = wh + (size_t)HID * KP;
  float* part = (float*)(w2h + 16 * HID);

  hipLaunchKernelGGL(prep_kernel, dim3(2048), dim3(256), 0, stream, x, W1, W2, xh, wh, w2h);
  hipLaunchKernelGGL(gemm_kernel, dim3(NCT, BATCH / BM), dim3(512), 0, stream,
                     xh, wh, w2h, b1, part);
  hipLaunchKernelGGL(reduce_kernel, dim3((BATCH * OUT_F + 255) / 256), dim3(256), 0, stream,
                     part, b2, out);
}

// Round 11
// 68.421 us; speedup vs baseline: 1.0157x; 1.0157x over previous
//
#include <hip/hip_runtime.h>
#include <cstdint>

// CovNet BNN: out = clip(x @ sign(W1)^T + b1, ±1) @ W2^T + b2
// B=8192, IN=784, HID=4096, OUT=10.
// R11 = R10 minus the scheduling walls (the m141 poison):
//   - NO sched_barrier(0) in the loop; NO manual lgkm waits between ds_reads
//     and MFMAs. The ds_reads are plain C++ loads -> the compiler tracks the
//     dependency and emits precise counted lgkmcnt per MFMA (m97 asm), and is
//     free to interleave next-phase reads under current-phase MFMAs.
//   - ONE plain lgkmcnt(0) right before the per-tile barrier: guarantees no
//     ds_read is in flight across the barrier (closes the WAR window against
//     next-tile gl_lds writes into the buffer those reads target).
// Everything else is R10's verified ledger:
//   ring-2 A, ring-3 B, per tile: {stA(t+1); RD12(S1,t,kk1); MFMA32(S0);
//   stB(t+2); lgkm0; WAITV(4); BARRIER; RD12(S0,t+1,kk0); MFMA32(S1)}.
//   vmcnt(4) certs A(t+1),B(t+1) (oldest 8 of 12 outstanding), leaves B(t+2)
//   in flight -- never drains mid-loop (tail: t=11 vmcnt(0), t=12 free).
// WAR audit: stA(t+1) overwrites A(t-1), whose reads drained at t-1's lgkm0 +
//   barrier. stB(t+2) -> slot (t+2)%3 holds B(t-1), same. Post-barrier reads
//   target only buffers certified by the preceding WAITV+BARRIER.
// Epilogue: R8 verbatim (fused GEMM2 via LDS; passed R2-R10, absmax 0.0625).

#define BATCH 8192
#define IN_F  784
#define HID   4096
#define OUT_F 10
#define KP    832     // padded K = 13*64
#define NKT   13
#define BM    256
#define BN    256
#define BK    64
#define NCT   (HID / BN)   // 16 col tiles
#define HCS   264          // epilogue hc row stride (f16)

typedef unsigned short u16;
typedef __attribute__((ext_vector_type(4))) unsigned short u16x4;
typedef __attribute__((ext_vector_type(8)))  _Float16 f16x8;
typedef __attribute__((ext_vector_type(4)))  float    f32x4;

#define BARRIER() do { asm volatile("" ::: "memory"); \
                       __builtin_amdgcn_s_barrier();  \
                       asm volatile("" ::: "memory"); } while (0)
#define WAITV(n)  asm volatile("s_waitcnt vmcnt(" #n ")" ::: "memory")
#define LGKM0()   asm volatile("s_waitcnt lgkmcnt(0)" ::: "memory")

__device__ __forceinline__ u16 f2h(float f) {
  union { _Float16 h; u16 u; } c;
  c.h = (_Float16)f;   // RNE
  return c.u;
}

__device__ __forceinline__ void gl_lds16(const void* g, void* l) {
  __builtin_amdgcn_global_load_lds(
      (const __attribute__((address_space(1))) uint32_t*)g,
      (__attribute__((address_space(3))) uint32_t*)l, 16, 0, 0);
}

// ---------------- prep: x -> f16 (padded), W1 -> sign f16 (padded), W2 -> [16][4096]
__global__ void prep_kernel(const float* __restrict__ x, const float* __restrict__ W1,
                            const float* __restrict__ W2,
                            u16* __restrict__ xh, u16* __restrict__ wh,
                            u16* __restrict__ w2h) {
  const int stride = gridDim.x * blockDim.x;
  const int gid = blockIdx.x * blockDim.x + threadIdx.x;
  const int KP4 = KP / 4;    // 208
  const int IN4 = IN_F / 4;  // 196
  const float4* x4 = (const float4*)x;
  const float4* w4 = (const float4*)W1;
  for (int i = gid; i < BATCH * KP4; i += stride) {
    int b = i / KP4, k = i - b * KP4;
    u16x4 o = {0, 0, 0, 0};
    if (k < IN4) {
      float4 v = x4[(size_t)b * IN4 + k];
      o[0] = f2h(v.x); o[1] = f2h(v.y); o[2] = f2h(v.z); o[3] = f2h(v.w);
    }
    *(u16x4*)&xh[(size_t)b * KP + k * 4] = o;
  }
  for (int i = gid; i < HID * KP4; i += stride) {
    int h = i / KP4, k = i - h * KP4;
    u16x4 o = {0, 0, 0, 0};
    if (k < IN4) {
      float4 v = w4[(size_t)h * IN4 + k];
      o[0] = v.x > 0.f ? 0x3C00 : (v.x < 0.f ? 0xBC00 : 0);
      o[1] = v.y > 0.f ? 0x3C00 : (v.y < 0.f ? 0xBC00 : 0);
      o[2] = v.z > 0.f ? 0x3C00 : (v.z < 0.f ? 0xBC00 : 0);
      o[3] = v.w > 0.f ? 0x3C00 : (v.w < 0.f ? 0xBC00 : 0);
    }
    *(u16x4*)&wh[(size_t)h * KP + k * 4] = o;
  }
  for (int i = gid; i < 16 * HID; i += stride) {
    int o = i >> 12, k = i & (HID - 1);
    w2h[i] = (o < OUT_F) ? f2h(W2[o * HID + k]) : (u16)0;
  }
}

// ---------------- main fused GEMM (256x256, 8 waves, 16x16x32, R11 pipeline)
__global__ void __launch_bounds__(512, 1) gemm_kernel(
    const u16* __restrict__ xh, const u16* __restrict__ wh,
    const u16* __restrict__ w2h, const float* __restrict__ b1,
    float* __restrict__ part) {
  __shared__ union {
    struct { u16 A[2][BM * BK]; u16 B[3][BN * BK]; } m;   // 64+96 = 160 KiB
    struct { u16 hc[128 * HCS]; u16 w2[16 * 256]; } e;    // ~74 KiB
  } sm;

  const int t   = threadIdx.x;
  const int ct  = blockIdx.x;   // col tile (HID), 0..15
  const int br  = blockIdx.y;   // row tile (BATCH), 0..31
  const int w   = t >> 6;       // wave 0..7
  const int l   = t & 63;
  const int wm  = w >> 2;       // 0..1: wave rows = wm*128 + mi*16 (mi 0..7)
  const int wn  = w & 3;        // 0..3: wave cols = wn*64  + nj*16 (nj 0..3)
  const int g   = l >> 4;
  const int r16 = l & 15;
  const int swz = (r16 & 7) << 3;   // f16-unit XOR (16B-slot granule)

  // staging: thread t covers 16B; per 64-row chunk: row = t>>3; source slot
  // pre-swizzled (rule #21): logical slot = (t&7)^(row&7); LDS dest linear.
  const int  srow  = t >> 3;
  const int  sslot = (t & 7) ^ (srow & 7);
  const u16* gA = xh + (size_t)(br * BM) * KP + sslot * 8;
  const u16* gB = wh + (size_t)(ct * BN) * KP + sslot * 8;

  auto stA = [&](int tile) {          // full A tile -> ring slot tile&1 (4 ops)
    const int b = tile & 1;
#pragma unroll
    for (int c = 0; c < 4; ++c)
      gl_lds16(gA + (size_t)(c * 64 + srow) * KP + tile * BK,
               &sm.m.A[b][c * 4096 + t * 8]);
  };
  auto stB = [&](int tile, int s) {   // full B tile -> ring slot s (4 ops)
#pragma unroll
    for (int c = 0; c < 4; ++c)
      gl_lds16(gB + (size_t)(c * 64 + srow) * KP + tile * BK,
               &sm.m.B[s][c * 4096 + t * 8]);
  };
  // reads apply the same XOR involution: phys slot = logical slot ^ (row&7)
  auto rdA = [&](int p, int mi, int kk) -> f16x8 {
    int row = wm * 128 + mi * 16 + r16;
    return *(const f16x8*)&sm.m.A[p][row * 64 + ((kk * 32 + g * 8) ^ swz)];
  };
  auto rdB = [&](int s, int nj, int kk) -> f16x8 {
    int row = wn * 64 + nj * 16 + r16;
    return *(const f16x8*)&sm.m.B[s][row * 64 + ((kk * 32 + g * 8) ^ swz)];
  };

  f32x4 acc[8][4] = {};       // [mi][nj]
  f16x8 af[2][8], bf[2][4];   // two named frag sets, static indices only

#define RD12(S, P, BS, KK) do {                                       \
    _Pragma("unroll") for (int mi_ = 0; mi_ < 8; ++mi_) af[S][mi_] = rdA(P, mi_, KK); \
    _Pragma("unroll") for (int nj_ = 0; nj_ < 4; ++nj_) bf[S][nj_] = rdB(BS, nj_, KK); \
  } while (0)
#define MFMA32(S) do {                                                \
    __builtin_amdgcn_s_setprio(1);                                    \
    _Pragma("unroll") for (int mi_ = 0; mi_ < 8; ++mi_)               \
      _Pragma("unroll") for (int nj_ = 0; nj_ < 4; ++nj_)             \
        acc[mi_][nj_] = __builtin_amdgcn_mfma_f32_16x16x32_f16(       \
            af[S][mi_], bf[S][nj_], acc[mi_][nj_], 0, 0, 0);          \
    __builtin_amdgcn_s_setprio(0);                                    \
  } while (0)

  // prologue: A(0),B(0) certified; B(1) stays in flight past the wait
  stA(0);
  stB(0, 0);
  stB(1, 1);
  WAITV(4);
  BARRIER();
  RD12(0, 0, 0, 0);   // tile 0 first-half frags

  int bs = 0;   // tt % 3
  for (int tt = 0; tt < NKT; ++tt) {
    const int p   = tt & 1;
    const int bs1 = (bs == 2) ? 0 : bs + 1;   // (tt+1) % 3
    const int bs2 = (bs == 0) ? 2 : bs - 1;   // (tt+2) % 3

    if (tt + 1 < NKT) stA(tt + 1);
    RD12(1, p, bs, 1);                 // own second-half frags (compiler
                                       //  interleaves their waits w/ MFMAs)
    MFMA32(0);                         // first-half (frags from end of t-1)
    if (tt + 2 < NKT) stB(tt + 2, bs2);
    LGKM0();                           // no ds_read in flight across barrier
    if      (tt < NKT - 2)  { WAITV(4); }  // certs A(t+1),B(t+1); B(t+2) flies
    else if (tt == NKT - 2) { WAITV(0); }  // tail drain
    if (tt + 1 < NKT) {
      BARRIER();                       // next-tile buffers valid chip-wide
      RD12(0, p ^ 1, bs1, 0);          // next tile first-half frags
    }
    MFMA32(1);                         // second-half

    bs = bs1;
  }

  // ---- epilogue: h = clip(acc + b1), fused GEMM2 through LDS (R8 verbatim) ----
  LGKM0();
  BARRIER();   // all waves' tile-12 reads drained; e.* overlays m.A/m.B
  {
    int row = t >> 5, sp = t & 31;
    int ls = (sp & 24) | ((sp ^ row) & 7);   // swizzled logical slot
    gl_lds16(w2h + (size_t)row * HID + ct * BN + ls * 8, &sm.e.w2[t * 8]);
  }
  float b1v[4];
#pragma unroll
  for (int ni = 0; ni < 4; ++ni) b1v[ni] = b1[ct * BN + wn * 64 + ni * 16 + r16];

  float* partBase = part + ((size_t)ct * BATCH + br * BM) * 16;

#pragma unroll
  for (int p = 0; p < 2; ++p) {
    if (p == 1) BARRIER();               // p=0 hc reads done before overwrite
    if (wm == p) {
#pragma unroll
      for (int mi = 0; mi < 8; ++mi)
#pragma unroll
        for (int ni = 0; ni < 4; ++ni)
#pragma unroll
          for (int r = 0; r < 4; ++r) {
            float v = acc[mi][ni][r] + b1v[ni];
            v = fminf(fmaxf(v, -1.f), 1.f);
            sm.e.hc[(mi * 16 + g * 4 + r) * HCS + wn * 64 + ni * 16 + r16] = f2h(v);
          }
    }
    if (p == 0) { WAITV(0); }            // w2 landed
    BARRIER();
    f32x4 acc2 = {};
#pragma unroll
    for (int kk = 0; kk < 8; ++kk) {
      f16x8 a2 = *(const f16x8*)&sm.e.hc[(w * 16 + r16) * HCS + kk * 32 + g * 8];
      int s   = kk * 4 + g;
      int sp2 = (s & 24) | ((s ^ r16) & 7);
      f16x8 b2f = *(const f16x8*)&sm.e.w2[r16 * 256 + sp2 * 8];
      acc2 = __builtin_amdgcn_mfma_f32_16x16x32_f16(a2, b2f, acc2, 0, 0, 0);
    }
#pragma unroll
    for (int r = 0; r < 4; ++r)
      partBase[(size_t)(p * 128 + w * 16 + g * 4 + r) * 16 + r16] = acc2[r];
  }
}

// ---------------- reduce partials over 16 col tiles + b2
__global__ void reduce_kernel(const float* __restrict__ part, const float* __restrict__ b2,
                              float* __restrict__ out) {
  int i = blockIdx.x * blockDim.x + threadIdx.x;
  if (i >= BATCH * OUT_F) return;
  int b = i / OUT_F, o = i - b * OUT_F;
  float acc = b2[o];
#pragma unroll
  for (int c = 0; c < NCT; ++c)
    acc += part[((size_t)c * BATCH + b) * 16 + o];
  out[i] = acc;
}

extern "C" void kernel_launch(void* const* d_in, const int* in_sizes, int n_in,
                              void* d_out, int out_size, void* d_ws, size_t ws_size,
                              hipStream_t stream) {
  const float* x  = (const float*)d_in[0];
  const float* W1 = (const float*)d_in[1];
  const float* b1 = (const float*)d_in[2];
  const float* W2 = (const float*)d_in[3];
  const float* b2 = (const float*)d_in[4];
  float* out = (float*)d_out;

  // ws layout (~29 MB): xh 13.6 MB | wh 6.8 MB | w2h 0.13 MB | part 8.4 MB
  u16* xh  = (u16*)d_ws;
  u16* wh  = xh + (size_t)BATCH * KP;
  u16* w2h = wh + (size_t)HID * KP;
  float* part = (float*)(w2h + 16 * HID);

  hipLaunchKernelGGL(prep_kernel, dim3(2048), dim3(256), 0, stream, x, W1, W2, xh, wh, w2h);
  hipLaunchKernelGGL(gemm_kernel, dim3(NCT, BATCH / BM), dim3(512), 0, stream,
                     xh, wh, w2h, b1, part);
  hipLaunchKernelGGL(reduce_kernel, dim3((BATCH * OUT_F + 255) / 256), dim3(256), 0, stream,
                     part, b2, out);
}

// Round 13
// 65.774 us; speedup vs baseline: 1.0566x; 1.0402x over previous
//
#include <hip/hip_runtime.h>
#include <cstdint>

// CovNet BNN: out = clip(x @ sign(W1)^T + b1, ±1) @ W2^T + b2
// B=8192, IN=784, HID=4096, OUT=10.
// R13 = R9's EXACT passing ledger (61.6us, absmax 0.0625) with the per-phase
// lgkmcnt(0)+sched_barrier(0) walls DELETED (the m141 order-pinning poison).
// R12's re-balanced ledger FAILED because B-fragment reads span the FULL B
// tile every phase (wave wn reads rows wn*64..wn*64+63) -> B(t) must be fully
// certified before P0(t); only A halves may certify late. R9 satisfies this:
//   stage order/tile t: P0:Ah0(t+1) P1:Bh0(t+1) P2:Bh1(t+1) P3:Ah1(t+1)
//   P3-end WAITV(2): outstanding 8 -> completes Ah0',Bh0',Bh1'; Ah1' flies
//   P0-end WAITV(2): outstanding {Ah1(t),Ah0(t+1)} -> completes Ah1(t)
//     (needed by P1); leaves Ah0(t+1).    [tail tt=12: P0-end WAITV(0)]
// No lgkm walls in the loop: ds_reads are plain C++ loads consumed by MFMAs
// within their phase -> compiler emits precise counted lgkmcnt before each
// MFMA cluster (completes reads before the phase's end barrier); asm
// "memory"-clobber barriers block cross-phase motion. WAR audit: each stage
// overwrites tile t-1 data whose reads completed >=2 barriers earlier.
// Prologue: stage Ah0,Bh0,Bh1,Ah1(0); WAITV(2) certs first 3; BARRIER.
// Epilogue: R9 verbatim (fused GEMM2 via LDS; passed R2-R11).

#define BATCH 8192
#define IN_F  784
#define HID   4096
#define OUT_F 10
#define KP    832     // padded K = 13*64
#define NKT   13
#define BM    256
#define BN    256
#define BK    64
#define NCT   (HID / BN)   // 16 col tiles
#define HCS   264          // epilogue hc row stride (f16)

typedef unsigned short u16;
typedef __attribute__((ext_vector_type(4))) unsigned short u16x4;
typedef __attribute__((ext_vector_type(8)))  _Float16 f16x8;
typedef __attribute__((ext_vector_type(4)))  float    f32x4;

#define BARRIER() do { asm volatile("" ::: "memory"); \
                       __builtin_amdgcn_s_barrier();  \
                       asm volatile("" ::: "memory"); } while (0)
#define WAITV(n)  asm volatile("s_waitcnt vmcnt(" #n ")" ::: "memory")
#define LGKM0()   asm volatile("s_waitcnt lgkmcnt(0)" ::: "memory")

__device__ __forceinline__ u16 f2h(float f) {
  union { _Float16 h; u16 u; } c;
  c.h = (_Float16)f;   // RNE
  return c.u;
}

__device__ __forceinline__ void gl_lds16(const void* g, void* l) {
  __builtin_amdgcn_global_load_lds(
      (const __attribute__((address_space(1))) uint32_t*)g,
      (__attribute__((address_space(3))) uint32_t*)l, 16, 0, 0);
}

// ---------------- prep: x -> f16 (padded), W1 -> sign f16 (padded), W2 -> [16][4096]
__global__ void prep_kernel(const float* __restrict__ x, const float* __restrict__ W1,
                            const float* __restrict__ W2,
                            u16* __restrict__ xh, u16* __restrict__ wh,
                            u16* __restrict__ w2h) {
  const int stride = gridDim.x * blockDim.x;
  const int gid = blockIdx.x * blockDim.x + threadIdx.x;
  const int KP4 = KP / 4;    // 208
  const int IN4 = IN_F / 4;  // 196
  const float4* x4 = (const float4*)x;
  const float4* w4 = (const float4*)W1;
  for (int i = gid; i < BATCH * KP4; i += stride) {
    int b = i / KP4, k = i - b * KP4;
    u16x4 o = {0, 0, 0, 0};
    if (k < IN4) {
      float4 v = x4[(size_t)b * IN4 + k];
      o[0] = f2h(v.x); o[1] = f2h(v.y); o[2] = f2h(v.z); o[3] = f2h(v.w);
    }
    *(u16x4*)&xh[(size_t)b * KP + k * 4] = o;
  }
  for (int i = gid; i < HID * KP4; i += stride) {
    int h = i / KP4, k = i - h * KP4;
    u16x4 o = {0, 0, 0, 0};
    if (k < IN4) {
      float4 v = w4[(size_t)h * IN4 + k];
      o[0] = v.x > 0.f ? 0x3C00 : (v.x < 0.f ? 0xBC00 : 0);
      o[1] = v.y > 0.f ? 0x3C00 : (v.y < 0.f ? 0xBC00 : 0);
      o[2] = v.z > 0.f ? 0x3C00 : (v.z < 0.f ? 0xBC00 : 0);
      o[3] = v.w > 0.f ? 0x3C00 : (v.w < 0.f ? 0xBC00 : 0);
    }
    *(u16x4*)&wh[(size_t)h * KP + k * 4] = o;
  }
  for (int i = gid; i < 16 * HID; i += stride) {
    int o = i >> 12, k = i & (HID - 1);
    w2h[i] = (o < OUT_F) ? f2h(W2[o * HID + k]) : (u16)0;
  }
}

// ---------------- main fused GEMM (256x256, 8 waves, 16x16x32, R9 ledger, no walls)
__global__ void __launch_bounds__(512, 2) gemm_kernel(
    const u16* __restrict__ xh, const u16* __restrict__ wh,
    const u16* __restrict__ w2h, const float* __restrict__ b1,
    float* __restrict__ part) {
  __shared__ union {
    struct { u16 A[2][BM * BK]; u16 B[2][BN * BK]; } m;   // 128 KiB
    struct { u16 hc[128 * HCS]; u16 w2[16 * 256]; } e;    // ~74 KiB
  } sm;

  const int t   = threadIdx.x;
  const int ct  = blockIdx.x;   // col tile (HID), 0..15
  const int br  = blockIdx.y;   // row tile (BATCH), 0..31
  const int w   = t >> 6;       // wave 0..7
  const int l   = t & 63;
  const int wm  = w >> 2;       // A row = MI*32 + wm*16 + r16 (M interleave)
  const int wn  = w & 3;        // B col = wn*64 + nj*16 + r16
  const int g   = l >> 4;
  const int r16 = l & 15;
  const int swz = (r16 & 7) << 3;   // f16-unit XOR (16B-slot granule)

  // staging: thread t covers 16B; per 64-row chunk: row = t>>3; source slot
  // pre-swizzled (rule #21): logical slot = (t&7)^(row&7); LDS dest linear.
  const int  srow  = t >> 3;
  const int  sslot = (t & 7) ^ (srow & 7);
  const u16* gA = xh + (size_t)(br * BM) * KP + sslot * 8;
  const u16* gB = wh + (size_t)(ct * BN) * KP + sslot * 8;

  auto stA2 = [&](int tile, int h) {   // A half h = rows h*128..h*128+127 (2 ops)
    const int b = tile & 1;
#pragma unroll
    for (int c = 2 * h; c < 2 * h + 2; ++c)
      gl_lds16(gA + (size_t)(c * 64 + srow) * KP + tile * BK,
               &sm.m.A[b][c * 4096 + t * 8]);
  };
  auto stB2 = [&](int tile, int h) {   // B half h = cols h*128..h*128+127 (2 ops)
    const int b = tile & 1;
#pragma unroll
    for (int c = 2 * h; c < 2 * h + 2; ++c)
      gl_lds16(gB + (size_t)(c * 64 + srow) * KP + tile * BK,
               &sm.m.B[b][c * 4096 + t * 8]);
  };
  // reads apply the same XOR involution: phys slot = logical slot ^ (row&7)
  auto rdA = [&](int p, int MI, int kk) -> f16x8 {   // MI 0..7; 0..3 in Ah0
    int row = MI * 32 + wm * 16 + r16;
    return *(const f16x8*)&sm.m.A[p][row * 64 + ((kk * 32 + g * 8) ^ swz)];
  };
  auto rdB = [&](int p, int nj, int kk) -> f16x8 {   // col-chunk wn only
    int row = wn * 64 + nj * 16 + r16;
    return *(const f16x8*)&sm.m.B[p][row * 64 + ((kk * 32 + g * 8) ^ swz)];
  };

  f32x4 acc[8][4] = {};   // [MI][nj]
  f16x8 af[4], bf0[4], bf1[4];

#define MFMA16(MH, BF) do {                                           \
    __builtin_amdgcn_s_setprio(1);                                    \
    _Pragma("unroll") for (int mi_ = 0; mi_ < 4; ++mi_)               \
      _Pragma("unroll") for (int nj_ = 0; nj_ < 4; ++nj_)             \
        acc[(MH) * 4 + mi_][nj_] = __builtin_amdgcn_mfma_f32_16x16x32_f16( \
            af[mi_], BF[nj_], acc[(MH) * 4 + mi_][nj_], 0, 0, 0);     \
    __builtin_amdgcn_s_setprio(0);                                    \
  } while (0)

  // prologue: Ah0(0),Bh0(0),Bh1(0),Ah1(0); certify first 3, Ah1(0) flies
  stA2(0, 0); stB2(0, 0); stB2(0, 1); stA2(0, 1);
  WAITV(2);
  BARRIER();

  for (int tt = 0; tt < NKT; ++tt) {
    const int  p    = tt & 1;
    const bool more = (tt + 1 < NKT);

    // ---- P0: Q(m0,k0) — 8 reads; stage Ah0(t+1) ----
#pragma unroll
    for (int mi = 0; mi < 4; ++mi) af[mi] = rdA(p, mi, 0);
#pragma unroll
    for (int nj = 0; nj < 4; ++nj) bf0[nj] = rdB(p, nj, 0);
    if (more) stA2(tt + 1, 0);
    BARRIER();
    MFMA16(0, bf0);
    if (more) { WAITV(2); } else { WAITV(0); }   // certs Ah1(t) for P1 reads
    BARRIER();

    // ---- P1: Q(m1,k0) — 4 reads, bf0 held; stage Bh0(t+1) ----
#pragma unroll
    for (int mi = 0; mi < 4; ++mi) af[mi] = rdA(p, 4 + mi, 0);
    if (more) stB2(tt + 1, 0);
    BARRIER();
    MFMA16(1, bf0);
    BARRIER();

    // ---- P2: Q(m0,k1) — 8 reads; stage Bh1(t+1) ----
#pragma unroll
    for (int mi = 0; mi < 4; ++mi) af[mi] = rdA(p, mi, 1);
#pragma unroll
    for (int nj = 0; nj < 4; ++nj) bf1[nj] = rdB(p, nj, 1);
    if (more) stB2(tt + 1, 1);
    BARRIER();
    MFMA16(0, bf1);
    BARRIER();

    // ---- P3: Q(m1,k1) — 4 reads, bf1 held; stage Ah1(t+1) ----
#pragma unroll
    for (int mi = 0; mi < 4; ++mi) af[mi] = rdA(p, 4 + mi, 1);
    if (more) stA2(tt + 1, 1);
    BARRIER();
    MFMA16(1, bf1);
    if (more) WAITV(2);   // certs Ah0',Bh0',Bh1'(t+1); Ah1' stays in flight
    BARRIER();
  }

  // ---- epilogue: h = clip(acc + b1), fused GEMM2 through LDS (R9 verbatim) ----
  LGKM0();
  BARRIER();   // e.* overlays m.A/m.B; all main-loop LDS traffic drained
  {
    int row = t >> 5, sp = t & 31;
    int ls = (sp & 24) | ((sp ^ row) & 7);   // swizzled logical slot
    gl_lds16(w2h + (size_t)row * HID + ct * BN + ls * 8, &sm.e.w2[t * 8]);
  }
  float b1v[4];
#pragma unroll
  for (int ni = 0; ni < 4; ++ni) b1v[ni] = b1[ct * BN + wn * 64 + ni * 16 + r16];

  float* partBase = part + ((size_t)ct * BATCH + br * BM) * 16;

#pragma unroll
  for (int p = 0; p < 2; ++p) {
    if (p == 1) BARRIER();               // p=0 hc reads done before overwrite
    // pass p writes global rows [p*128,+128) = acc[p*4+mi][*];
    // local hc row = mi*32 + wm*16 + g*4 + r  (M-interleaved mapping)
#pragma unroll
    for (int mi = 0; mi < 4; ++mi)
#pragma unroll
      for (int ni = 0; ni < 4; ++ni)
#pragma unroll
        for (int r = 0; r < 4; ++r) {
          float v = acc[p * 4 + mi][ni][r] + b1v[ni];
          v = fminf(fmaxf(v, -1.f), 1.f);
          sm.e.hc[(mi * 32 + wm * 16 + g * 4 + r) * HCS + wn * 64 + ni * 16 + r16] = f2h(v);
        }
    if (p == 0) { WAITV(0); }            // w2 landed
    BARRIER();
    f32x4 acc2 = {};
#pragma unroll
    for (int kk = 0; kk < 8; ++kk) {
      f16x8 a2 = *(const f16x8*)&sm.e.hc[(w * 16 + r16) * HCS + kk * 32 + g * 8];
      int s   = kk * 4 + g;
      int sp2 = (s & 24) | ((s ^ r16) & 7);
      f16x8 b2f = *(const f16x8*)&sm.e.w2[r16 * 256 + sp2 * 8];
      acc2 = __builtin_amdgcn_mfma_f32_16x16x32_f16(a2, b2f, acc2, 0, 0, 0);
    }
#pragma unroll
    for (int r = 0; r < 4; ++r)
      partBase[(size_t)(p * 128 + w * 16 + g * 4 + r) * 16 + r16] = acc2[r];
  }
}

// ---------------- reduce partials over 16 col tiles + b2
__global__ void reduce_kernel(const float* __restrict__ part, const float* __restrict__ b2,
                              float* __restrict__ out) {
  int i = blockIdx.x * blockDim.x + threadIdx.x;
  if (i >= BATCH * OUT_F) return;
  int b = i / OUT_F, o = i - b * OUT_F;
  float acc = b2[o];
#pragma unroll
  for (int c = 0; c < NCT; ++c)
    acc += part[((size_t)c * BATCH + b) * 16 + o];
  out[i] = acc;
}

extern "C" void kernel_launch(void* const* d_in, const int* in_sizes, int n_in,
                              void* d_out, int out_size, void* d_ws, size_t ws_size,
                              hipStream_t stream) {
  const float* x  = (const float*)d_in[0];
  const float* W1 = (const float*)d_in[1];
  const float* b1 = (const float*)d_in[2];
  const float* W2 = (const float*)d_in[3];
  const float* b2 = (const float*)d_in[4];
  float* out = (float*)d_out;

  // ws layout (~29 MB): xh 13.6 MB | wh 6.8 MB | w2h 0.13 MB | part 8.4 MB
  u16* xh  = (u16*)d_ws;
  u16* wh  = xh + (size_t)BATCH * KP;
  u16* w2h = wh + (size_t)HID * KP;
  float* part = (float*)(w2h + 16 * HID);

  hipLaunchKernelGGL(prep_kernel, dim3(2048), dim3(256), 0, stream, x, W1, W2, xh, wh, w2h);
  hipLaunchKernelGGL(gemm_kernel, dim3(NCT, BATCH / BM), dim3(512), 0, stream,
                     xh, wh, w2h, b1, part);
  hipLaunchKernelGGL(reduce_kernel, dim3((BATCH * OUT_F + 255) / 256), dim3(256), 0, stream,
                     part, b2, out);
}